// Round 6
// baseline (1444.515 us; speedup 1.0000x reference)
//
#include <hip/hip_runtime.h>
#include <stdint.h>

#define B_SZ   8192
#define IN_DIM 512
#define HID    256
#define PROJ   128

typedef __attribute__((ext_vector_type(8))) short bf16x8;
typedef __attribute__((ext_vector_type(4))) float f32x4;

#define GLDS16(gp, lp) __builtin_amdgcn_global_load_lds( \
    (const __attribute__((address_space(1))) void*)(gp), \
    (__attribute__((address_space(3))) void*)(lp), 16, 0, 0)

__device__ __forceinline__ unsigned short f2bf(float f) {
    union { float f; uint32_t u; } c; c.f = f;
    uint32_t u = c.u;
    uint32_t r = (u + 0x7fffu + ((u >> 16) & 1u)) >> 16;   // RNE
    return (unsigned short)r;
}
__device__ __forceinline__ float bfhi(uint32_t v) {
    union { uint32_t u; float f; } c; c.u = v & 0xffff0000u; return c.f;
}
__device__ __forceinline__ float bflo(uint32_t v) {
    union { uint32_t u; float f; } c; c.u = v << 16; return c.f;
}

// ---------------- shared: f32 -> bf16x8 load helper ----------------------
__device__ __forceinline__ bf16x8 ld_cvt8(const float* __restrict__ s) {
    float4 a = *(const float4*)s;
    float4 b = *(const float4*)(s + 4);
    bf16x8 r;
    r[0] = (short)f2bf(a.x); r[1] = (short)f2bf(a.y);
    r[2] = (short)f2bf(a.z); r[3] = (short)f2bf(a.w);
    r[4] = (short)f2bf(b.x); r[5] = (short)f2bf(b.y);
    r[6] = (short)f2bf(b.z); r[7] = (short)f2bf(b.w);
    return r;
}

// ------- K0 (fused prep): one kernel, four independent block ranges ------
//   [0,2048)    : W2 f32 -> bf16
//   [2048,3072) : x transpose -> xTb (bf16)
//   [3072,3328) : k1  h = relu(ft @ W1^T + b1) -> hb (bf16)
//   [3328,3584) : k2  out[b,p] = sum_i x[b,i]*b2[p*512+i]  (bias term)
// Fusing removes 2 launch gaps (~12us each) and lets the parts overlap.
__global__ __launch_bounds__(256) void k0_prep(
        const float4* __restrict__ W2, ushort4* __restrict__ W2b,
        const float* __restrict__ x, unsigned short* __restrict__ xTb,
        const float* __restrict__ ft, const float* __restrict__ W1,
        const float* __restrict__ b1, unsigned short* __restrict__ hb,
        const float* __restrict__ b2, float* __restrict__ out) {
    __shared__ float tile[64][65];
    const int bid = blockIdx.x;
    const f32x4 z4 = {0.f, 0.f, 0.f, 0.f};

    if (bid < 2048) {
        // ---- W2 convert ----
        const int nW2 = (PROJ * IN_DIM * HID) / 4;
        const int stride = 2048 * 256;
        for (int i = bid * 256 + threadIdx.x; i < nW2; i += stride) {
            float4 v = W2[i];
            ushort4 o;
            o.x = f2bf(v.x); o.y = f2bf(v.y); o.z = f2bf(v.z); o.w = f2bf(v.w);
            W2b[i] = o;
        }
    } else if (bid < 3072) {
        // ---- x transpose ----
        const int tb = bid - 2048;
        const int bi = tb & 7, bb = tb >> 3;
        const int i0 = bi * 64, b0 = bb * 64;
        const int t = threadIdx.x;
        const int c = t & 63, r4 = t >> 6;
        #pragma unroll
        for (int rr = 0; rr < 64; rr += 4)
            tile[rr + r4][c] = x[(size_t)(b0 + rr + r4) * IN_DIM + i0 + c];
        __syncthreads();
        #pragma unroll
        for (int rr = 0; rr < 64; rr += 4)
            xTb[(size_t)(i0 + rr + r4) * B_SZ + b0 + c] = f2bf(tile[c][rr + r4]);
    } else if (bid < 3328) {
        // ---- k1: hidden layer ----
        const int lane = threadIdx.x & 63;
        const int wv   = threadIdx.x >> 6;
        const int l15  = lane & 15, q = lane >> 4;
        const int b0 = (bid - 3072) * 32;
        const int n0 = wv * 64;

        f32x4 acc[2][4];
        #pragma unroll
        for (int mt = 0; mt < 2; ++mt)
            #pragma unroll
            for (int nt = 0; nt < 4; ++nt) acc[mt][nt] = z4;

        for (int kq = 0; kq < 16; ++kq) {
            const int koff = kq * 32 + q * 8;
            bf16x8 a[2], bb[4];
            #pragma unroll
            for (int mt = 0; mt < 2; ++mt)
                a[mt] = ld_cvt8(ft + (size_t)(b0 + mt*16 + l15) * IN_DIM + koff);
            #pragma unroll
            for (int nt = 0; nt < 4; ++nt)
                bb[nt] = ld_cvt8(W1 + (size_t)(n0 + nt*16 + l15) * IN_DIM + koff);
            #pragma unroll
            for (int mt = 0; mt < 2; ++mt)
                #pragma unroll
                for (int nt = 0; nt < 4; ++nt)
                    acc[mt][nt] = __builtin_amdgcn_mfma_f32_16x16x32_bf16(
                        a[mt], bb[nt], acc[mt][nt], 0, 0, 0);
        }
        #pragma unroll
        for (int nt = 0; nt < 4; ++nt) {
            float bias = b1[n0 + nt*16 + l15];
            #pragma unroll
            for (int mt = 0; mt < 2; ++mt)
                #pragma unroll
                for (int r = 0; r < 4; ++r) {
                    float v = acc[mt][nt][r] + bias;
                    v = fmaxf(v, 0.f);
                    hb[(size_t)(b0 + mt*16 + q*4 + r) * HID + n0 + nt*16 + l15] = f2bf(v);
                }
        }
    } else {
        // ---- k2: bias-term GEMM ----
        const int lane = threadIdx.x & 63;
        const int wv   = threadIdx.x >> 6;
        const int l15  = lane & 15, q = lane >> 4;
        const int b0 = (bid - 3328) * 32;
        const int n0 = wv * 32;

        f32x4 acc[2][2];
        #pragma unroll
        for (int mt = 0; mt < 2; ++mt)
            #pragma unroll
            for (int nt = 0; nt < 2; ++nt) acc[mt][nt] = z4;

        for (int kq = 0; kq < 16; ++kq) {
            const int koff = kq * 32 + q * 8;
            bf16x8 a[2], bb[2];
            #pragma unroll
            for (int mt = 0; mt < 2; ++mt)
                a[mt] = ld_cvt8(x + (size_t)(b0 + mt*16 + l15) * IN_DIM + koff);
            #pragma unroll
            for (int nt = 0; nt < 2; ++nt)
                bb[nt] = ld_cvt8(b2 + (size_t)(n0 + nt*16 + l15) * IN_DIM + koff);
            #pragma unroll
            for (int mt = 0; mt < 2; ++mt)
                #pragma unroll
                for (int nt = 0; nt < 2; ++nt)
                    acc[mt][nt] = __builtin_amdgcn_mfma_f32_16x16x32_bf16(
                        a[mt], bb[nt], acc[mt][nt], 0, 0, 0);
        }
        #pragma unroll
        for (int mt = 0; mt < 2; ++mt)
            #pragma unroll
            for (int nt = 0; nt < 2; ++nt)
                #pragma unroll
                for (int r = 0; r < 4; ++r)
                    out[(size_t)(b0 + mt*16 + q*4 + r) * PROJ + n0 + nt*16 + l15]
                        = acc[mt][nt][r];
    }
}

// ---------------- K3: out[b,p] += sum_i x[b,i]*(sum_k h[b,k]*W2[p,i,k]) --
// R5's verified structure (mt=4/pp=1, conflict-free 128B-row LDS, counted
// vmcnt(2), x single-buffer restage, afr K-half reload at t==15).
// ONLY change: __launch_bounds__(256,4). R5's (256,3) was the binding
// occupancy constraint (measured 32% ~ exactly 3 blocks); VGPR=84 and
// 32KB LDS permit 5 blocks/CU (160KB exactly) once the allocator is
// relaxed -> more independent blocks to hide the per-step latency chain.
__global__ __launch_bounds__(256, 4) void k3_main(
        const unsigned short* __restrict__ W2b,
        const unsigned short* __restrict__ hb,
        const unsigned short* __restrict__ xTb,
        float* __restrict__ out) {
    __shared__ unsigned short w2t[2][2][32 * 64];  // [dbuf][khalf][32r][64k] = 16 KB
    __shared__ unsigned short xt[32 * 256];        // [32 i][256 b] = 16 KB
    const int tid  = threadIdx.x;
    const int lane = tid & 63;
    const int wv   = tid >> 6;
    const int l15  = lane & 15, q = lane >> 4;
    const int pgrp = blockIdx.x & 127;            // stride-128 => same XCD per p
    const int bsup = blockIdx.x >> 7;             // 0..31
    const int p0   = pgrp;
    const int b0blk = bsup * 256;
    const int b0w  = b0blk + wv * 64;             // 64 b-rows per wave
    const f32x4 z4 = {0.f, 0.f, 0.f, 0.f};

    // ---- h fragments for current K-half (kh=0 now; reload at t==15) ----
    bf16x8 afr[4][4];
    #pragma unroll
    for (int mt = 0; mt < 4; ++mt) {
        const unsigned short* hrow = hb + (size_t)(b0w + mt*16 + l15) * HID + q * 8;
        #pragma unroll
        for (int kq = 0; kq < 4; ++kq)
            afr[mt][kq] = *(const bf16x8*)(hrow + kq * 32);
    }

    // ---- glds source pointers (per-lane, pre-swizzled) ----
    const unsigned short* wsp[2];
    #pragma unroll
    for (int jj = 0; jj < 2; ++jj) {
        const int rl = wv*8 + (lane >> 3);
        const int c  = (lane & 7) ^ (lane >> 3);
        wsp[jj] = W2b + ((size_t)p0 * IN_DIM + rl) * HID + jj * 64 + c * 8;
    }
    const unsigned short* xsp[4];
    #pragma unroll
    for (int jj = 0; jj < 4; ++jj) {
        const int r = wv*8 + jj*2 + (lane >> 5);
        const int c = (lane & 31) ^ (r & 7);
        xsp[jj] = xTb + (size_t)r * B_SZ + b0blk + c * 8;
    }

    float oacc[4][4];
    #pragma unroll
    for (int mt = 0; mt < 4; ++mt)
        #pragma unroll
        for (int r = 0; r < 4; ++r) oacc[mt][r] = 0.f;

#define STAGE_W2(BUFI, TT) do {                                           \
    const int _kh = (TT) >> 4, _ic = (TT) & 15;                           \
    const size_t _add = (size_t)(_ic * 32) * HID + _kh * 128;             \
    _Pragma("unroll")                                                     \
    for (int _jj = 0; _jj < 2; ++_jj)                                     \
        GLDS16(wsp[_jj] + _add, &w2t[BUFI][_jj][wv * 512]);               \
} while (0)

#define STAGE_X(TT) do {                                                  \
    const size_t _add = (size_t)(((TT) & 15) * 32) * B_SZ;                \
    _Pragma("unroll")                                                     \
    for (int _jj = 0; _jj < 4; ++_jj)                                     \
        GLDS16(xsp[_jj] + _add, &xt[(wv*8 + _jj*2) * 256]);               \
} while (0)

#define COMPUTE() do {                                                    \
    _Pragma("unroll")                                                     \
    for (int sub = 0; sub < 2; ++sub) {                                   \
        const int rloc = sub*16 + l15;                                    \
        const int sw   = rloc & 7;                                        \
        uint2 xv[4];                                                      \
        _Pragma("unroll")                                                 \
        for (int mt = 0; mt < 4; ++mt) {                                  \
            const int cc = wv*8 + mt*2 + (q >> 1);                        \
            const int ss = cc ^ sw;                                       \
            xv[mt] = *(const uint2*)(&xt[rloc*256 + ss*8 + (q & 1)*4]);   \
        }                                                                 \
        bf16x8 bfr[4];                                                    \
        _Pragma("unroll")                                                 \
        for (int kq = 0; kq < 4; ++kq) {                                  \
            const int khf = kq >> 1;                                      \
            const int ch  = (q + 4*(kq & 1)) ^ sw;                        \
            bfr[kq] = *(const bf16x8*)(Lw + khf*2048 + rloc*64 + ch*8);   \
        }                                                                 \
        f32x4 D[4];                                                       \
        _Pragma("unroll")                                                 \
        for (int mt = 0; mt < 4; ++mt)                                    \
            D[mt] = __builtin_amdgcn_mfma_f32_16x16x32_bf16(              \
                afr[mt][0], bfr[0], z4, 0, 0, 0);                         \
        _Pragma("unroll")                                                 \
        for (int kq = 1; kq < 4; ++kq)                                    \
            _Pragma("unroll")                                             \
            for (int mt = 0; mt < 4; ++mt)                                \
                D[mt] = __builtin_amdgcn_mfma_f32_16x16x32_bf16(          \
                    afr[mt][kq], bfr[kq], D[mt], 0, 0, 0);                \
        _Pragma("unroll")                                                 \
        for (int mt = 0; mt < 4; ++mt) {                                  \
            oacc[mt][0] = fmaf(D[mt][0], bflo(xv[mt].x), oacc[mt][0]);    \
            oacc[mt][1] = fmaf(D[mt][1], bfhi(xv[mt].x), oacc[mt][1]);    \
            oacc[mt][2] = fmaf(D[mt][2], bflo(xv[mt].y), oacc[mt][2]);    \
            oacc[mt][3] = fmaf(D[mt][3], bfhi(xv[mt].y), oacc[mt][3]);    \
        }                                                                 \
    }                                                                     \
} while (0)

    // ---- prologue: queue = [w2(0) 2, x(0) 4, w2(1) 2] ----
    STAGE_W2(0, 0);
    STAGE_X(0);
    STAGE_W2(1, 1);

    #pragma unroll 1
    for (int t = 0; t < 32; ++t) {
        // need w2(t), x(t) landed; w2(t+1) (2 newest) may stay in flight
        if (t < 31) asm volatile("s_waitcnt vmcnt(2)" ::: "memory");
        else        asm volatile("s_waitcnt vmcnt(0)" ::: "memory");
        __builtin_amdgcn_s_barrier();     // all waves' tile-t data visible
        asm volatile("" ::: "memory");

        const unsigned short* Lw = &w2t[t & 1][0][0];
        COMPUTE();

        asm volatile("" ::: "memory");
        __builtin_amdgcn_s_barrier();     // all waves done reading buffers
        asm volatile("" ::: "memory");

        if (t == 15) {   // reload afr for kh=1; BEFORE stage => older in vm
            #pragma unroll  // queue, so the next vmcnt(2) covers it (no drain)
            for (int mt = 0; mt < 4; ++mt) {
                const unsigned short* hrow =
                    hb + (size_t)(b0w + mt*16 + l15) * HID + 128 + q * 8;
                #pragma unroll
                for (int kq = 0; kq < 4; ++kq)
                    afr[mt][kq] = *(const bf16x8*)(hrow + kq * 32);
            }
        }
        if (t < 31) STAGE_X(t + 1);
        if (t < 30) STAGE_W2(t & 1, t + 2);
    }
#undef STAGE_W2
#undef STAGE_X
#undef COMPUTE

    // ---- epilogue: reduce over 16 i-lanes, accumulate onto k2's bias ----
    #pragma unroll
    for (int mt = 0; mt < 4; ++mt)
        #pragma unroll
        for (int r = 0; r < 4; ++r) {
            float v = oacc[mt][r];
            v += __shfl_xor(v, 1, 16);
            v += __shfl_xor(v, 2, 16);
            v += __shfl_xor(v, 4, 16);
            v += __shfl_xor(v, 8, 16);
            if (l15 == 0)
                out[(size_t)(b0w + mt*16 + q*4 + r) * PROJ + p0] += v;
        }
}

extern "C" void kernel_launch(void* const* d_in, const int* in_sizes, int n_in,
                              void* d_out, int out_size, void* d_ws, size_t ws_size,
                              hipStream_t stream) {
    const float* ft = (const float*)d_in[0];
    const float* x  = (const float*)d_in[1];
    const float* W1 = (const float*)d_in[2];
    const float* b1 = (const float*)d_in[3];
    const float* W2 = (const float*)d_in[4];
    const float* b2 = (const float*)d_in[5];
    float* out = (float*)d_out;

    char* ws = (char*)d_ws;
    unsigned short* W2b = (unsigned short*)(ws);             // 33,554,432 B
    unsigned short* hb  = (unsigned short*)(ws + 33554432);  //  4,194,304 B
    unsigned short* xTb = (unsigned short*)(ws + 37748736);  //  8,388,608 B

    hipLaunchKernelGGL(k0_prep, dim3(3584), dim3(256), 0, stream,
        (const float4*)W2, (ushort4*)W2b, x, xTb, ft, W1, b1, hb, b2, out);
    hipLaunchKernelGGL(k3_main, dim3(4096), dim3(256), 0, stream, W2b, hb, xTb, out);
}

// Round 7
// 539.353 us; speedup vs baseline: 2.6782x; 2.6782x over previous
//
#include <hip/hip_runtime.h>
#include <stdint.h>

#define B_SZ   8192
#define IN_DIM 512
#define HID    256
#define PROJ   128

typedef __attribute__((ext_vector_type(8))) short bf16x8;
typedef __attribute__((ext_vector_type(4))) float f32x4;

#define GLDS16(gp, lp) __builtin_amdgcn_global_load_lds( \
    (const __attribute__((address_space(1))) void*)(gp), \
    (__attribute__((address_space(3))) void*)(lp), 16, 0, 0)

__device__ __forceinline__ unsigned short f2bf(float f) {
    union { float f; uint32_t u; } c; c.f = f;
    uint32_t u = c.u;
    uint32_t r = (u + 0x7fffu + ((u >> 16) & 1u)) >> 16;   // RNE
    return (unsigned short)r;
}
__device__ __forceinline__ float bfhi(uint32_t v) {
    union { uint32_t u; float f; } c; c.u = v & 0xffff0000u; return c.f;
}
__device__ __forceinline__ float bflo(uint32_t v) {
    union { uint32_t u; float f; } c; c.u = v << 16; return c.f;
}

// ---------------- shared: f32 -> bf16x8 load helper ----------------------
__device__ __forceinline__ bf16x8 ld_cvt8(const float* __restrict__ s) {
    float4 a = *(const float4*)s;
    float4 b = *(const float4*)(s + 4);
    bf16x8 r;
    r[0] = (short)f2bf(a.x); r[1] = (short)f2bf(a.y);
    r[2] = (short)f2bf(a.z); r[3] = (short)f2bf(a.w);
    r[4] = (short)f2bf(b.x); r[5] = (short)f2bf(b.y);
    r[6] = (short)f2bf(b.z); r[7] = (short)f2bf(b.w);
    return r;
}

// ------- K0 (fused prep): one kernel, four independent block ranges ------
//   [0,2048)    : W2 f32 -> bf16
//   [2048,3072) : x transpose -> xTb (bf16)
//   [3072,3328) : k1  h = relu(ft @ W1^T + b1) -> hb (bf16)
//   [3328,3584) : k2  out[b,p] = sum_i x[b,i]*b2[p*512+i]  (bias term)
__global__ __launch_bounds__(256) void k0_prep(
        const float4* __restrict__ W2, ushort4* __restrict__ W2b,
        const float* __restrict__ x, unsigned short* __restrict__ xTb,
        const float* __restrict__ ft, const float* __restrict__ W1,
        const float* __restrict__ b1, unsigned short* __restrict__ hb,
        const float* __restrict__ b2, float* __restrict__ out) {
    __shared__ float tile[64][65];
    const int bid = blockIdx.x;
    const f32x4 z4 = {0.f, 0.f, 0.f, 0.f};

    if (bid < 2048) {
        // ---- W2 convert ----
        const int nW2 = (PROJ * IN_DIM * HID) / 4;
        const int stride = 2048 * 256;
        for (int i = bid * 256 + threadIdx.x; i < nW2; i += stride) {
            float4 v = W2[i];
            ushort4 o;
            o.x = f2bf(v.x); o.y = f2bf(v.y); o.z = f2bf(v.z); o.w = f2bf(v.w);
            W2b[i] = o;
        }
    } else if (bid < 3072) {
        // ---- x transpose ----
        const int tb = bid - 2048;
        const int bi = tb & 7, bb = tb >> 3;
        const int i0 = bi * 64, b0 = bb * 64;
        const int t = threadIdx.x;
        const int c = t & 63, r4 = t >> 6;
        #pragma unroll
        for (int rr = 0; rr < 64; rr += 4)
            tile[rr + r4][c] = x[(size_t)(b0 + rr + r4) * IN_DIM + i0 + c];
        __syncthreads();
        #pragma unroll
        for (int rr = 0; rr < 64; rr += 4)
            xTb[(size_t)(i0 + rr + r4) * B_SZ + b0 + c] = f2bf(tile[c][rr + r4]);
    } else if (bid < 3328) {
        // ---- k1: hidden layer ----
        const int lane = threadIdx.x & 63;
        const int wv   = threadIdx.x >> 6;
        const int l15  = lane & 15, q = lane >> 4;
        const int b0 = (bid - 3072) * 32;
        const int n0 = wv * 64;

        f32x4 acc[2][4];
        #pragma unroll
        for (int mt = 0; mt < 2; ++mt)
            #pragma unroll
            for (int nt = 0; nt < 4; ++nt) acc[mt][nt] = z4;

        for (int kq = 0; kq < 16; ++kq) {
            const int koff = kq * 32 + q * 8;
            bf16x8 a[2], bb[4];
            #pragma unroll
            for (int mt = 0; mt < 2; ++mt)
                a[mt] = ld_cvt8(ft + (size_t)(b0 + mt*16 + l15) * IN_DIM + koff);
            #pragma unroll
            for (int nt = 0; nt < 4; ++nt)
                bb[nt] = ld_cvt8(W1 + (size_t)(n0 + nt*16 + l15) * IN_DIM + koff);
            #pragma unroll
            for (int mt = 0; mt < 2; ++mt)
                #pragma unroll
                for (int nt = 0; nt < 4; ++nt)
                    acc[mt][nt] = __builtin_amdgcn_mfma_f32_16x16x32_bf16(
                        a[mt], bb[nt], acc[mt][nt], 0, 0, 0);
        }
        #pragma unroll
        for (int nt = 0; nt < 4; ++nt) {
            float bias = b1[n0 + nt*16 + l15];
            #pragma unroll
            for (int mt = 0; mt < 2; ++mt)
                #pragma unroll
                for (int r = 0; r < 4; ++r) {
                    float v = acc[mt][nt][r] + bias;
                    v = fmaxf(v, 0.f);
                    hb[(size_t)(b0 + mt*16 + q*4 + r) * HID + n0 + nt*16 + l15] = f2bf(v);
                }
        }
    } else {
        // ---- k2: bias-term GEMM ----
        const int lane = threadIdx.x & 63;
        const int wv   = threadIdx.x >> 6;
        const int l15  = lane & 15, q = lane >> 4;
        const int b0 = (bid - 3328) * 32;
        const int n0 = wv * 32;

        f32x4 acc[2][2];
        #pragma unroll
        for (int mt = 0; mt < 2; ++mt)
            #pragma unroll
            for (int nt = 0; nt < 2; ++nt) acc[mt][nt] = z4;

        for (int kq = 0; kq < 16; ++kq) {
            const int koff = kq * 32 + q * 8;
            bf16x8 a[2], bb[2];
            #pragma unroll
            for (int mt = 0; mt < 2; ++mt)
                a[mt] = ld_cvt8(x + (size_t)(b0 + mt*16 + l15) * IN_DIM + koff);
            #pragma unroll
            for (int nt = 0; nt < 2; ++nt)
                bb[nt] = ld_cvt8(b2 + (size_t)(n0 + nt*16 + l15) * IN_DIM + koff);
            #pragma unroll
            for (int mt = 0; mt < 2; ++mt)
                #pragma unroll
                for (int nt = 0; nt < 2; ++nt)
                    acc[mt][nt] = __builtin_amdgcn_mfma_f32_16x16x32_bf16(
                        a[mt], bb[nt], acc[mt][nt], 0, 0, 0);
        }
        #pragma unroll
        for (int mt = 0; mt < 2; ++mt)
            #pragma unroll
            for (int nt = 0; nt < 2; ++nt)
                #pragma unroll
                for (int r = 0; r < 4; ++r)
                    out[(size_t)(b0 + mt*16 + q*4 + r) * PROJ + n0 + nt*16 + l15]
                        = acc[mt][nt][r];
    }
}

// ---------------- K3: out[b,p] += sum_i x[b,i]*(sum_k h[b,k]*W2[p,i,k]) --
// R5 structure, two fixes:
//  (1) REVERT to (256,3): R6's (256,4) squeezed VGPR 84->64, afr spilled to
//      scratch (FETCH 4GB, WRITE 444MB, 3.8x slower). Floor is ~84 VGPR.
//  (2) x gets a 2-STEP PREFETCH LEAD (double-buffered, staged at t+2 with
//      W2). R5 staged x(t+1) and waited it at the very next loop top: a
//      full L2/HBM latency serialized into EVERY step - the reason R5's
//      conflict fix bought ~nothing. Now both streams are 2-deep; loop top
//      waits vmcnt(6) = drain {w2(t),x(t)}, leave {w2(t+1),x(t+1)} in
//      flight. vmcnt precedes barrier-1 => cross-wave visibility holds.
__global__ __launch_bounds__(256, 3) void k3_main(
        const unsigned short* __restrict__ W2b,
        const unsigned short* __restrict__ hb,
        const unsigned short* __restrict__ xTb,
        float* __restrict__ out) {
    __shared__ unsigned short w2t[2][2][32 * 64];  // [dbuf][khalf][32r][64k] = 16 KB
    __shared__ unsigned short xt[2][32 * 256];     // [dbuf][32 i][256 b] = 32 KB
    const int tid  = threadIdx.x;
    const int lane = tid & 63;
    const int wv   = tid >> 6;
    const int l15  = lane & 15, q = lane >> 4;
    const int pgrp = blockIdx.x & 127;            // stride-128 => same XCD per p
    const int bsup = blockIdx.x >> 7;             // 0..31
    const int p0   = pgrp;
    const int b0blk = bsup * 256;
    const int b0w  = b0blk + wv * 64;             // 64 b-rows per wave
    const f32x4 z4 = {0.f, 0.f, 0.f, 0.f};

    // ---- h fragments for current K-half (kh=0 now; reload at t==15) ----
    bf16x8 afr[4][4];
    #pragma unroll
    for (int mt = 0; mt < 4; ++mt) {
        const unsigned short* hrow = hb + (size_t)(b0w + mt*16 + l15) * HID + q * 8;
        #pragma unroll
        for (int kq = 0; kq < 4; ++kq)
            afr[mt][kq] = *(const bf16x8*)(hrow + kq * 32);
    }

    // ---- glds source pointers (per-lane, pre-swizzled) ----
    const unsigned short* wsp[2];
    #pragma unroll
    for (int jj = 0; jj < 2; ++jj) {
        const int rl = wv*8 + (lane >> 3);
        const int c  = (lane & 7) ^ (lane >> 3);
        wsp[jj] = W2b + ((size_t)p0 * IN_DIM + rl) * HID + jj * 64 + c * 8;
    }
    const unsigned short* xsp[4];
    #pragma unroll
    for (int jj = 0; jj < 4; ++jj) {
        const int r = wv*8 + jj*2 + (lane >> 5);
        const int c = (lane & 31) ^ (r & 7);
        xsp[jj] = xTb + (size_t)r * B_SZ + b0blk + c * 8;
    }

    float oacc[4][4];
    #pragma unroll
    for (int mt = 0; mt < 4; ++mt)
        #pragma unroll
        for (int r = 0; r < 4; ++r) oacc[mt][r] = 0.f;

#define STAGE_W2(BUFI, TT) do {                                           \
    const int _kh = (TT) >> 4, _ic = (TT) & 15;                           \
    const size_t _add = (size_t)(_ic * 32) * HID + _kh * 128;             \
    _Pragma("unroll")                                                     \
    for (int _jj = 0; _jj < 2; ++_jj)                                     \
        GLDS16(wsp[_jj] + _add, &w2t[BUFI][_jj][wv * 512]);               \
} while (0)

#define STAGE_X(BUFI, TT) do {                                            \
    const size_t _add = (size_t)(((TT) & 15) * 32) * B_SZ;                \
    _Pragma("unroll")                                                     \
    for (int _jj = 0; _jj < 4; ++_jj)                                     \
        GLDS16(xsp[_jj] + _add, &xt[BUFI][(wv*8 + _jj*2) * 256]);         \
} while (0)

#define COMPUTE() do {                                                    \
    _Pragma("unroll")                                                     \
    for (int sub = 0; sub < 2; ++sub) {                                   \
        const int rloc = sub*16 + l15;                                    \
        const int sw   = rloc & 7;                                        \
        uint2 xv[4];                                                      \
        _Pragma("unroll")                                                 \
        for (int mt = 0; mt < 4; ++mt) {                                  \
            const int cc = wv*8 + mt*2 + (q >> 1);                        \
            const int ss = cc ^ sw;                                       \
            xv[mt] = *(const uint2*)(&Lx[rloc*256 + ss*8 + (q & 1)*4]);   \
        }                                                                 \
        bf16x8 bfr[4];                                                    \
        _Pragma("unroll")                                                 \
        for (int kq = 0; kq < 4; ++kq) {                                  \
            const int khf = kq >> 1;                                      \
            const int ch  = (q + 4*(kq & 1)) ^ sw;                        \
            bfr[kq] = *(const bf16x8*)(Lw + khf*2048 + rloc*64 + ch*8);   \
        }                                                                 \
        f32x4 D[4];                                                       \
        _Pragma("unroll")                                                 \
        for (int mt = 0; mt < 4; ++mt)                                    \
            D[mt] = __builtin_amdgcn_mfma_f32_16x16x32_bf16(              \
                afr[mt][0], bfr[0], z4, 0, 0, 0);                         \
        _Pragma("unroll")                                                 \
        for (int kq = 1; kq < 4; ++kq)                                    \
            _Pragma("unroll")                                             \
            for (int mt = 0; mt < 4; ++mt)                                \
                D[mt] = __builtin_amdgcn_mfma_f32_16x16x32_bf16(          \
                    afr[mt][kq], bfr[kq], D[mt], 0, 0, 0);                \
        _Pragma("unroll")                                                 \
        for (int mt = 0; mt < 4; ++mt) {                                  \
            oacc[mt][0] = fmaf(D[mt][0], bflo(xv[mt].x), oacc[mt][0]);    \
            oacc[mt][1] = fmaf(D[mt][1], bfhi(xv[mt].x), oacc[mt][1]);    \
            oacc[mt][2] = fmaf(D[mt][2], bflo(xv[mt].y), oacc[mt][2]);    \
            oacc[mt][3] = fmaf(D[mt][3], bfhi(xv[mt].y), oacc[mt][3]);    \
        }                                                                 \
    }                                                                     \
} while (0)

    // ---- prologue: tiles 0 and 1 fully in flight (w2+x each) ----
    STAGE_W2(0, 0);
    STAGE_X(0, 0);
    STAGE_W2(1, 1);
    STAGE_X(1, 1);

    #pragma unroll 1
    for (int t = 0; t < 32; ++t) {
        // drain {w2(t),x(t)} (6 oldest); {w2(t+1),x(t+1)} stay in flight
        if (t < 31) asm volatile("s_waitcnt vmcnt(6)" ::: "memory");
        else        asm volatile("s_waitcnt vmcnt(0)" ::: "memory");
        __builtin_amdgcn_s_barrier();     // all waves' tile-t data visible
        asm volatile("" ::: "memory");

        const unsigned short* Lw = &w2t[t & 1][0][0];
        const unsigned short* Lx = &xt[t & 1][0];
        COMPUTE();

        asm volatile("" ::: "memory");
        __builtin_amdgcn_s_barrier();     // all waves done reading buffers
        asm volatile("" ::: "memory");

        if (t == 15) {   // reload afr for kh=1; BEFORE stages => older in vm
            #pragma unroll  // queue, drained by the vmcnt(6) at top of t=16
            for (int mt = 0; mt < 4; ++mt) {
                const unsigned short* hrow =
                    hb + (size_t)(b0w + mt*16 + l15) * HID + 128 + q * 8;
                #pragma unroll
                for (int kq = 0; kq < 4; ++kq)
                    afr[mt][kq] = *(const bf16x8*)(hrow + kq * 32);
            }
        }
        if (t < 30) {
            STAGE_W2(t & 1, t + 2);       // into the buffers just released
            STAGE_X(t & 1, t + 2);
        }
    }
#undef STAGE_W2
#undef STAGE_X
#undef COMPUTE

    // ---- epilogue: reduce over 16 i-lanes, accumulate onto k2's bias ----
    #pragma unroll
    for (int mt = 0; mt < 4; ++mt)
        #pragma unroll
        for (int r = 0; r < 4; ++r) {
            float v = oacc[mt][r];
            v += __shfl_xor(v, 1, 16);
            v += __shfl_xor(v, 2, 16);
            v += __shfl_xor(v, 4, 16);
            v += __shfl_xor(v, 8, 16);
            if (l15 == 0)
                out[(size_t)(b0w + mt*16 + q*4 + r) * PROJ + p0] += v;
        }
}

extern "C" void kernel_launch(void* const* d_in, const int* in_sizes, int n_in,
                              void* d_out, int out_size, void* d_ws, size_t ws_size,
                              hipStream_t stream) {
    const float* ft = (const float*)d_in[0];
    const float* x  = (const float*)d_in[1];
    const float* W1 = (const float*)d_in[2];
    const float* b1 = (const float*)d_in[3];
    const float* W2 = (const float*)d_in[4];
    const float* b2 = (const float*)d_in[5];
    float* out = (float*)d_out;

    char* ws = (char*)d_ws;
    unsigned short* W2b = (unsigned short*)(ws);             // 33,554,432 B
    unsigned short* hb  = (unsigned short*)(ws + 33554432);  //  4,194,304 B
    unsigned short* xTb = (unsigned short*)(ws + 37748736);  //  8,388,608 B

    hipLaunchKernelGGL(k0_prep, dim3(3584), dim3(256), 0, stream,
        (const float4*)W2, (ushort4*)W2b, x, xTb, ft, W1, b1, hb, b2, out);
    hipLaunchKernelGGL(k3_main, dim3(4096), dim3(256), 0, stream, W2b, hb, xTb, out);
}